// Round 3
// baseline (399.669 us; speedup 1.0000x reference)
//
#include <hip/hip_runtime.h>
#include <hip/hip_fp16.h>

typedef _Float16 half8 __attribute__((ext_vector_type(8)));
typedef _Float16 half4v __attribute__((ext_vector_type(4)));
typedef float float4v __attribute__((ext_vector_type(4)));

#define BLOCK 256
#define ROWS_PER_BLOCK 64
// LDS row pitch in halfs: 96 data + 8 pad -> 208 B rows (16B-aligned for b128).
#define ROWPITCH 104

// Pre-converted f16 weight fragments: each lane's bfrag[s][t] is contiguous 16B.
// g_wh[(s*2+t)*512 + lane*8 + j] = w_s[(t*16+(lane&15))*32 + (lane>>4)*8 + j]
__device__ _Float16 g_wh[6 * 512];

__global__ void prep_weights(const float* __restrict__ w0,
                             const float* __restrict__ w1,
                             const float* __restrict__ w2) {
    const int t = threadIdx.x;           // 0..383
    const int st = t >> 6;               // s*2+tt, 0..5
    const int lane = t & 63;
    const int s = st >> 1, tt = st & 1;
    const float* w = (s == 0) ? w0 : (s == 1) ? w1 : w2;
    const int o = tt * 16 + (lane & 15);
    const int k = (lane >> 4) * 8;
    #pragma unroll
    for (int j = 0; j < 8; ++j)
        g_wh[st * 512 + lane * 8 + j] = (_Float16)w[o * 32 + k + j];
}

// x (fp32) -> xh (fp16), 8 elements per thread. NT read: x is dead after this.
__global__ __launch_bounds__(256) void prep_x(const float* __restrict__ x,
                                              _Float16* __restrict__ xh,
                                              int total) {
    const int i = (blockIdx.x * 256 + threadIdx.x) * 8;
    if (i < total) {
        float4v a = __builtin_nontemporal_load((const float4v*)(x + i));
        float4v b = __builtin_nontemporal_load((const float4v*)(x + i + 4));
        half8 h = {(_Float16)a.x, (_Float16)a.y, (_Float16)a.z, (_Float16)a.w,
                   (_Float16)b.x, (_Float16)b.y, (_Float16)b.z, (_Float16)b.w};
        *(half8*)(xh + i) = h;   // cached store: gathers re-read this
    }
}

// ---------------- fp16-gather main kernel (primary path) ----------------
__global__ __launch_bounds__(BLOCK) void face_conv_f16(
    const _Float16* __restrict__ xh,
    const float* __restrict__ bias,
    const int* __restrict__ fn,
    float* __restrict__ out,
    int N)
{
    __shared__ _Float16 A[4][16 * ROWPITCH];

    const int tid  = threadIdx.x;
    const int wave = tid >> 6;
    const int lane = tid & 63;
    const int m16  = lane & 15;   // MFMA col / row id
    const int quad = lane >> 4;   // MFMA k-group
    const int rloc = lane >> 2;   // gather: local row 0..15
    const int m4   = lane & 3;    // gather: channel group (8 halves)

    half8 bfrag[3][2];
    #pragma unroll
    for (int s = 0; s < 3; ++s)
        #pragma unroll
        for (int t = 0; t < 2; ++t)
            bfrag[s][t] = *(const half8*)(g_wh + (s * 2 + t) * 512 + lane * 8);
    const float bias0 = bias[m16];
    const float bias1 = bias[16 + m16];

    const int base = blockIdx.x * ROWS_PER_BLOCK + wave * 16;
    _Float16* Aw = A[wave];

    // ---- Phase A: one shot — 9 gathers cover all 16 rows of the wave ----
    int r = base + rloc;
    if (r >= N) r = N - 1;                   // grid covers N exactly; safety
    const int* fr = fn + (long)r * 9;
    int idx[9];
    #pragma unroll
    for (int j = 0; j < 9; ++j) idx[j] = __builtin_nontemporal_load(fr + j);

    half8 v[9];
    #pragma unroll
    for (int j = 0; j < 9; ++j) {
        const int id = idx[j];
        if ((unsigned)id < (unsigned)N) {
            v[j] = *(const half8*)(xh + (long)id * 32 + m4 * 8);
        } else {
            v[j] = (half8){0, 0, 0, 0, 0, 0, 0, 0};
        }
    }
    const half8 g0 = v[0];
    const half8 g1 = (v[1] + v[3]) + (v[5] + v[7]);   // v_pk_add_f16
    const half8 g2 = (v[2] + v[4]) + (v[6] + v[8]);

    _Float16* dst = Aw + rloc * ROWPITCH + m4 * 8;
    *(half8*)(dst)      = g0;
    *(half8*)(dst + 32) = g1;
    *(half8*)(dst + 64) = g2;

    __syncthreads();

    // ---- Phase B: 6 MFMAs per wave (16 rows x 32 outs, K=96) ----
    float4v acc0 = {0.f, 0.f, 0.f, 0.f}, acc1 = {0.f, 0.f, 0.f, 0.f};
    #pragma unroll
    for (int s = 0; s < 3; ++s) {
        half8 a = *(half8*)(Aw + m16 * ROWPITCH + s * 32 + quad * 8);
        acc0 = __builtin_amdgcn_mfma_f32_16x16x32_f16(a, bfrag[s][0], acc0, 0, 0, 0);
        acc1 = __builtin_amdgcn_mfma_f32_16x16x32_f16(a, bfrag[s][1], acc1, 0, 0, 0);
    }

    #pragma unroll
    for (int i = 0; i < 4; ++i) {
        const int rr = base + quad * 4 + i;
        if (rr < N) {
            __builtin_nontemporal_store(acc0[i] + bias0, &out[(long)rr * 32 + m16]);
            __builtin_nontemporal_store(acc1[i] + bias1, &out[(long)rr * 32 + 16 + m16]);
        }
    }
}

// ---------------- fp32-gather fallback (if d_ws too small) ----------------
__global__ __launch_bounds__(BLOCK) void face_conv_f32(
    const float* __restrict__ x,
    const float* __restrict__ bias,
    const int* __restrict__ fn,
    float* __restrict__ out,
    int N)
{
    __shared__ _Float16 A[4][16 * ROWPITCH];
    const int tid  = threadIdx.x;
    const int wave = tid >> 6;
    const int lane = tid & 63;
    const int m16  = lane & 15;
    const int quad = lane >> 4;
    const int oct  = lane >> 3;
    const int m8   = lane & 7;

    half8 bfrag[3][2];
    #pragma unroll
    for (int s = 0; s < 3; ++s)
        #pragma unroll
        for (int t = 0; t < 2; ++t)
            bfrag[s][t] = *(const half8*)(g_wh + (s * 2 + t) * 512 + lane * 8);
    const float bias0 = bias[m16];
    const float bias1 = bias[16 + m16];

    const int base = blockIdx.x * ROWS_PER_BLOCK + wave * 16;
    _Float16* Aw = A[wave];

    int idx[2][9];
    #pragma unroll
    for (int it = 0; it < 2; ++it) {
        int r = base + it * 8 + oct;
        r = (r < N) ? r : (N - 1);
        const int* fr = fn + (long)r * 9;
        #pragma unroll
        for (int j = 0; j < 9; ++j) idx[it][j] = __builtin_nontemporal_load(fr + j);
    }
    #pragma unroll
    for (int it = 0; it < 2; ++it) {
        float4v v[9];
        #pragma unroll
        for (int j = 0; j < 9; ++j) {
            const int id = idx[it][j];
            if ((unsigned)id < (unsigned)N) v[j] = *(const float4v*)(x + (long)id * 32 + m8 * 4);
            else                            v[j] = (float4v){0.f, 0.f, 0.f, 0.f};
        }
        const float4v g0 = v[0];
        const float4v g1 = v[1] + v[3] + v[5] + v[7];
        const float4v g2 = v[2] + v[4] + v[6] + v[8];
        _Float16* dst = Aw + (it * 8 + oct) * ROWPITCH + m8 * 4;
        *(half4v*)(dst)      = (half4v){(_Float16)g0.x, (_Float16)g0.y, (_Float16)g0.z, (_Float16)g0.w};
        *(half4v*)(dst + 32) = (half4v){(_Float16)g1.x, (_Float16)g1.y, (_Float16)g1.z, (_Float16)g1.w};
        *(half4v*)(dst + 64) = (half4v){(_Float16)g2.x, (_Float16)g2.y, (_Float16)g2.z, (_Float16)g2.w};
    }
    __syncthreads();

    float4v acc0 = {0.f, 0.f, 0.f, 0.f}, acc1 = {0.f, 0.f, 0.f, 0.f};
    #pragma unroll
    for (int s = 0; s < 3; ++s) {
        half8 a = *(half8*)(Aw + m16 * ROWPITCH + s * 32 + quad * 8);
        acc0 = __builtin_amdgcn_mfma_f32_16x16x32_f16(a, bfrag[s][0], acc0, 0, 0, 0);
        acc1 = __builtin_amdgcn_mfma_f32_16x16x32_f16(a, bfrag[s][1], acc1, 0, 0, 0);
    }
    #pragma unroll
    for (int i = 0; i < 4; ++i) {
        const int rr = base + quad * 4 + i;
        if (rr < N) {
            __builtin_nontemporal_store(acc0[i] + bias0, &out[(long)rr * 32 + m16]);
            __builtin_nontemporal_store(acc1[i] + bias1, &out[(long)rr * 32 + 16 + m16]);
        }
    }
}

extern "C" void kernel_launch(void* const* d_in, const int* in_sizes, int n_in,
                              void* d_out, int out_size, void* d_ws, size_t ws_size,
                              hipStream_t stream) {
    const float* x    = (const float*)d_in[0];
    const float* w0   = (const float*)d_in[1];
    const float* w1   = (const float*)d_in[2];
    const float* w2   = (const float*)d_in[3];
    const float* bias = (const float*)d_in[4];
    const int*   fn   = (const int*)d_in[5];
    float* out = (float*)d_out;

    const int total = in_sizes[0];       // N * 32
    const int N = total / 32;
    const int blocks = (N + ROWS_PER_BLOCK - 1) / ROWS_PER_BLOCK;

    prep_weights<<<1, 384, 0, stream>>>(w0, w1, w2);

    const size_t xh_bytes = (size_t)total * sizeof(_Float16);
    if (ws_size >= xh_bytes) {
        _Float16* xh = (_Float16*)d_ws;
        const int pblocks = (total / 8 + 255) / 256;
        prep_x<<<pblocks, 256, 0, stream>>>(x, xh, total);
        face_conv_f16<<<blocks, BLOCK, 0, stream>>>(xh, bias, fn, out, N);
    } else {
        face_conv_f32<<<blocks, BLOCK, 0, stream>>>(x, bias, fn, out, N);
    }
}